// Round 21
// baseline (601.137 us; speedup 1.0000x reference)
//
#include <hip/hip_runtime.h>

typedef float fv2 __attribute__((ext_vector_type(2)));
typedef float fv4 __attribute__((ext_vector_type(4)));
typedef float fv16 __attribute__((ext_vector_type(16)));
typedef _Float16 hfv8 __attribute__((ext_vector_type(8)));
typedef unsigned short u16v4 __attribute__((ext_vector_type(4)));
typedef unsigned short u16v8 __attribute__((ext_vector_type(8)));

#define B_DIM 4
#define L_DIM 8192
#define D_DIM 1024
#define H_NUM 16
#define NSEG 16
#define SEG_S 512
#define M_TOK (B_DIM * L_DIM)  // 32768

__device__ __forceinline__ unsigned short f2h(float f) {
  return __builtin_bit_cast(unsigned short, (_Float16)f);  // v_cvt_f16_f32 RNE
}
__device__ __forceinline__ float h2f(unsigned short u) {
  return (float)__builtin_bit_cast(_Float16, u);
}

// ---------------- fused fp32 -> fp16 conversions (weights + x, ONE launch) ----------------
__global__ __launch_bounds__(256) void conv_all(
    const float* __restrict__ wq, const float* __restrict__ wk,
    const float* __restrict__ wv, const float* __restrict__ wo,
    const float* __restrict__ x,
    unsigned short* __restrict__ wqkv16, unsigned short* __restrict__ wo16,
    unsigned short* __restrict__ x16) {
  const int W4 = D_DIM * D_DIM / 4;
  const int X4 = (M_TOK * D_DIM) / 4;
  const int blk = blockIdx.x;
  const float* src;
  unsigned short* dst;
  int n4, bid0, nblk;
  if (blk < 64)        { src = wq; dst = wqkv16;                              n4 = W4; bid0 = 0;   nblk = 64; }
  else if (blk < 128)  { src = wk; dst = wqkv16 + (size_t)D_DIM * D_DIM;      n4 = W4; bid0 = 64;  nblk = 64; }
  else if (blk < 192)  { src = wv; dst = wqkv16 + (size_t)2 * D_DIM * D_DIM;  n4 = W4; bid0 = 128; nblk = 64; }
  else if (blk < 256)  { src = wo; dst = wo16;                                n4 = W4; bid0 = 192; nblk = 64; }
  else                 { src = x;  dst = x16;                                 n4 = X4; bid0 = 256; nblk = 2048; }
  const int stride = nblk * 256;
  for (int i = (blk - bid0) * 256 + threadIdx.x; i < n4; i += stride) {
    fv4 v = reinterpret_cast<const fv4*>(src)[i];
    u16v4 p;
#pragma unroll
    for (int j = 0; j < 4; ++j) p[j] = f2h(v[j]);
    reinterpret_cast<u16v4*>(dst)[i] = p;
  }
}

// ---------------- C = A @ B^T, 32x32x16 fp16 MFMA, gload_lds, wide wave tile ----------------
// Block 256x128, 4 waves (2Mx2N), wave tile 128x64 = 4x2 tiles of 32x32.
// 3 LDS buffers, depth-2 prefetch, counted vmcnt(6) (T4), ONE barrier per phase
// (verified r16/r18 skeleton). Swizzle unchanged: inverse-swz global source,
// read chunk ^ (row>>1)&3 — bank-balanced for the 32-row read pattern.
// 32x32x16 raises MFMA pipe throughput ~17% and halves MFMA instr count.
// A frag: row=l&31, k=8*(l>>5)+j (analog of validated 16x16x32 mapping).
// C/D (m74/m101, HW-verified): col=lane&31, row=(reg&3)+8*(reg>>2)+4*(lane>>5).
template <int QKV>
__global__ __launch_bounds__(256, 2) void gemm_bt(
    const _Float16* __restrict__ A16, const _Float16* __restrict__ B16,
    float* __restrict__ C, const float* __restrict__ bias,
    unsigned short* __restrict__ Oq, unsigned short* __restrict__ Ok,
    unsigned short* __restrict__ Ov, int M, int NTILES, int K) {
  __shared__ _Float16 sA[3][8192];  // 256 rows x 32 k
  __shared__ _Float16 sB[3][4096];  // 128 rows x 32 k
  const int tid = threadIdx.x;
  const int lane = tid & 63;
  const int wv = tid >> 6;
  const int wr = wv >> 1, wc = wv & 1;
  const int l31 = lane & 31, l5 = lane >> 5;

  const int hw = blockIdx.x;
  const int xcd = hw & 7;
  const int rem = hw >> 3;
  const int ntile = rem % NTILES;
  const int yhi = rem / NTILES;
  const int mtile = yhi * 8 + xcd;
  const int mBase = mtile * 256;
  const int nBase = ntile * 128;

  fv16 acc[4][2] = {};

  const int srow = lane >> 2;
  const int cgx = ((lane & 3) ^ ((lane >> 3) & 3)) * 8;
  const long aStageBase = (long)(mBase + wv * 64 + srow) * K + cgx;
  const long bStageBase = (long)(nBase + wv * 32 + srow) * K + cgx;
  const int fsw = (l31 >> 1) & 3;          // read-side swizzle f(row)
  const int arowW = wr * 128 + l31;        // + mt*32
  const int browW = wc * 64 + l31;         // + nt*32

  auto STAGE = [&](int t, int bi) {
#pragma unroll
    for (int i = 0; i < 4; ++i)
      __builtin_amdgcn_global_load_lds(
          (const __attribute__((address_space(1))) void*)(A16 + aStageBase + (long)i * 16 * K + t * 32),
          (__attribute__((address_space(3))) void*)&sA[bi][wv * 2048 + i * 512], 16, 0, 0);
#pragma unroll
    for (int i = 0; i < 2; ++i)
      __builtin_amdgcn_global_load_lds(
          (const __attribute__((address_space(1))) void*)(B16 + bStageBase + (long)i * 16 * K + t * 32),
          (__attribute__((address_space(3))) void*)&sB[bi][wv * 1024 + i * 512], 16, 0, 0);
  };
  auto COMPUTE = [&](int bi) {
#pragma unroll
    for (int ks = 0; ks < 2; ++ks) {
      const int ch = ((2 * ks + l5) ^ fsw) * 8;  // LDS chunk offset (fp16 units)
      hfv8 fa[4], fb[2];
#pragma unroll
      for (int mt = 0; mt < 4; ++mt)
        fa[mt] = *(const hfv8*)&sA[bi][(arowW + mt * 32) * 32 + ch];
#pragma unroll
      for (int nt = 0; nt < 2; ++nt)
        fb[nt] = *(const hfv8*)&sB[bi][(browW + nt * 32) * 32 + ch];
      __builtin_amdgcn_s_setprio(1);
#pragma unroll
      for (int mt = 0; mt < 4; ++mt)
#pragma unroll
        for (int nt = 0; nt < 2; ++nt)
          acc[mt][nt] = __builtin_amdgcn_mfma_f32_32x32x16_f16(fa[mt], fb[nt], acc[mt][nt], 0, 0, 0);
      __builtin_amdgcn_s_setprio(0);
    }
  };

  const int NT = K / 32;  // 32
  STAGE(0, 0);
  STAGE(1, 1);
  for (int t = 0; t < NT; ++t) {
    if (t < NT - 1)
      asm volatile("s_waitcnt vmcnt(6)" ::: "memory");
    else
      asm volatile("s_waitcnt vmcnt(0)" ::: "memory");
    __builtin_amdgcn_s_barrier();
    if (t + 2 < NT) STAGE(t + 2, (t + 2) % 3);
    COMPUTE(t % 3);
    asm volatile("s_waitcnt lgkmcnt(0)" ::: "memory");
  }

  // C/D layout (m74/m101): col = lane&31, row = (reg&3) + 8*(reg>>2) + 4*(lane>>5)
  const int crowW = mBase + wr * 128 + 4 * l5;   // + mt*32 + q*8 + r
  const int ccolW = nBase + wc * 64 + l31;       // + nt*32
  if (QKV) {
    const int which = nBase >> 10;  // 0=Q 1=K 2=V, uniform per block
    unsigned short* outs = (which == 0) ? Oq : (which == 1) ? Ok : Ov;
#pragma unroll
    for (int nt = 0; nt < 2; ++nt) {
      const int col = (ccolW + nt * 32) & 1023;
#pragma unroll
      for (int mt = 0; mt < 4; ++mt)
#pragma unroll
        for (int q = 0; q < 4; ++q)
#pragma unroll
          for (int r = 0; r < 4; ++r)
            outs[(long)(crowW + mt * 32 + q * 8 + r) * 1024 + col] =
                f2h(acc[mt][nt][q * 4 + r]);
    }
  } else {
#pragma unroll
    for (int nt = 0; nt < 2; ++nt) {
      const int col = ccolW + nt * 32;
      const float bvn = bias ? bias[col] : 0.f;
#pragma unroll
      for (int mt = 0; mt < 4; ++mt)
#pragma unroll
        for (int q = 0; q < 4; ++q)
#pragma unroll
          for (int r = 0; r < 4; ++r)
            C[(long)(crowW + mt * 32 + q * 8 + r) * 1024 + col] =
                acc[mt][nt][q * 4 + r] + bvn;
    }
  }
}

// ---------------- per-(b,seg,h) outer products: U = akT.v, ak split fp16 ----------------
__global__ __launch_bounds__(256) void seg_outer_mfma(
    const unsigned short* __restrict__ K16, const unsigned short* __restrict__ V16,
    float* __restrict__ U, float* __restrict__ Zs) {
  __shared__ _Float16 sAh[64 * 64], sAl[64 * 64];
  __shared__ _Float16 sVh[64 * 64];
  __shared__ float sZf[64];
  const int bid = blockIdx.x;
  const int b = bid >> 8, seg = (bid >> 4) & 15, h = bid & 15;
  const int tid = threadIdx.x;
  const int lane = tid & 63, w = tid >> 6;
  const int g = lane >> 4, ln16 = lane & 15;
  const long base = ((long)b * L_DIM + (long)seg * SEG_S) * D_DIM + h * 64;

  if (tid < 64) sZf[tid] = 0.f;
  fv4 acc[4] = {};
  float zacc = 0.f;
  const int strow = tid & 63;
  const int sg0 = (tid >> 6) * 16;
  const int wsw = (strow & 7) << 3;
  const int rsw = (ln16 & 7) << 3;

  for (int c = 0; c < 8; ++c) {
    __syncthreads();
#pragma unroll
    for (int jj = 0; jj < 2; ++jj) {
      u16v8 ah, al, vh;
#pragma unroll
      for (int i = 0; i < 8; ++i) {
        const long gidx = base + (long)(c * 64 + sg0 + jj * 8 + i) * D_DIM + strow;
        const float kv = h2f(K16[gidx]);
        const float a = kv > 0.f ? kv + 1.f : __expf(kv);
        zacc += a;
        const unsigned short hb = f2h(a);
        ah[i] = hb;
        al[i] = f2h(a - h2f(hb));
        vh[i] = V16[gidx];
      }
      const int col = (sg0 + jj * 8) ^ wsw;
      *(u16v8*)&sAh[strow * 64 + col] = ah;
      *(u16v8*)&sAl[strow * 64 + col] = al;
      *(u16v8*)&sVh[strow * 64 + col] = vh;
    }
    __syncthreads();
#pragma unroll
    for (int kf = 0; kf < 2; ++kf) {
      const int so = (kf * 32 + g * 8) ^ rsw;
      hfv8 aH = *(const hfv8*)&sAh[(w * 16 + ln16) * 64 + so];
      hfv8 aL = *(const hfv8*)&sAl[(w * 16 + ln16) * 64 + so];
      __builtin_amdgcn_s_setprio(1);
#pragma unroll
      for (int et = 0; et < 4; ++et) {
        hfv8 bH = *(const hfv8*)&sVh[(et * 16 + ln16) * 64 + so];
        acc[et] = __builtin_amdgcn_mfma_f32_16x16x32_f16(aH, bH, acc[et], 0, 0, 0);
        acc[et] = __builtin_amdgcn_mfma_f32_16x16x32_f16(aL, bH, acc[et], 0, 0, 0);
      }
      __builtin_amdgcn_s_setprio(0);
    }
  }
  atomicAdd(&sZf[strow], zacc);
  __syncthreads();

  const long ub = (long)bid * 4096;
#pragma unroll
  for (int et = 0; et < 4; ++et)
#pragma unroll
    for (int r = 0; r < 4; ++r)
      U[ub + (long)(w * 16 + g * 4 + r) * 64 + et * 16 + ln16] = acc[et][r];
  if (tid < 64) Zs[(long)bid * 64 + tid] = sZf[tid];
}

// ---------------- exclusive prefix over segments (per b,h) ----------------
__global__ __launch_bounds__(256) void seg_prefix(
    const float* __restrict__ U, const float* __restrict__ Zs,
    float* __restrict__ Mem, float* __restrict__ Zp) {
  const int bh = blockIdx.x;
  const int b = bh >> 4, h = bh & 15;
  const int jc = blockIdx.y;
  const int tid = threadIdx.x;
  for (int j = jc * 512 + tid; j < jc * 512 + 512; j += 256) {
    float run = 0.f;
#pragma unroll
    for (int t = 0; t < NSEG; ++t) {
      const long idx = ((long)(b * 256 + t * 16 + h)) * 4096 + j;
      Mem[idx] = run;
      run += U[idx];
    }
  }
  if (jc == 0 && tid < 64) {
    float run = 0.f;
#pragma unroll
    for (int t = 0; t < NSEG; ++t) {
      const long idx = ((long)(b * 256 + t * 16 + h)) * 64 + tid;
      Zp[idx] = run;
      run += Zs[idx];
    }
  }
}

// ---------------- MFMA segment attention: 2 query-sets per block (r18/r20 verbatim) ----------------
__global__ __launch_bounds__(512, 4) void attn_seg_mfma(
    const unsigned short* __restrict__ Q16, const unsigned short* __restrict__ K16,
    const unsigned short* __restrict__ V16, const int* __restrict__ mask,
    const float* __restrict__ Mem, const float* __restrict__ Zp,
    const float* __restrict__ betas, unsigned short* __restrict__ Op16) {
  __shared__ _Float16 sKh[64 * 72];
  __shared__ _Float16 sVTh[64 * 64];
  __shared__ _Float16 sP[8][16 * 72];
  __shared__ float sMadd[64], sZ[64], sGate[64];

  const int bx = (blockIdx.x & 7) * 256 + (blockIdx.x >> 3);  // T1 bijective
  const int qpair = bx & 1, h = (bx >> 1) & 15, seg = (bx >> 5) & 15, b = bx >> 9;
  const int shb = b * 256 + seg * 16 + h;
  const int tid = threadIdx.x;
  const int lane = tid & 63, w = tid >> 6;
  const int g = lane >> 4, ln16 = lane & 15;
  const int rsw = (ln16 & 7) << 3;

  int qglob[2];
  hfv8 qh[2][2];
#pragma unroll
  for (int s = 0; s < 2; ++s) {
    qglob[s] = b * L_DIM + seg * SEG_S + qpair * 256 + s * 128 + w * 16 + ln16;
    const long qb = (long)qglob[s] * D_DIM + h * 64;
#pragma unroll
    for (int dt = 0; dt < 2; ++dt)
      qh[s][dt] = *(const hfv8*)&Q16[qb + dt * 32 + g * 8];
  }

  fv4 O[2][4] = {};
  float m_run[2] = {-1e30f, -1e30f}, l_run[2] = {0.f, 0.f};
  const long kvbase0 = ((long)b * L_DIM + (long)seg * SEG_S) * D_DIM + h * 64;

  for (int c = 0; c < 8; ++c) {
    __syncthreads();
    {
      const int row = tid >> 3, d0 = (tid & 7) * 8;
      const long ga = kvbase0 + (long)(c * 64 + row) * D_DIM + d0;
      *(u16v8*)&sKh[row * 72 + d0] = *(const u16v8*)&K16[ga];
    }
    {
      const int e = tid & 63, kg = (tid >> 6) * 8;
      u16v8 hv;
#pragma unroll
      for (int j = 0; j < 8; ++j)
        hv[j] = V16[kvbase0 + (long)(c * 64 + kg + j) * D_DIM + e];
      *(u16v8*)&sVTh[e * 64 + (kg ^ ((e & 7) << 3))] = hv;
    }
    if (tid < 64)
      sMadd[tid] = (mask[b * L_DIM + seg * SEG_S + c * 64 + tid] == 0) ? -1e9f : 0.f;
    __syncthreads();

    fv4 madd[4];
#pragma unroll
    for (int kt = 0; kt < 4; ++kt) madd[kt] = *(const fv4*)&sMadd[kt * 16 + g * 4];

#pragma unroll
    for (int s = 0; s < 2; ++s) {
      fv4 sc[4];
#pragma unroll
      for (int kt = 0; kt < 4; ++kt) {
        const int ro = (kt * 16 + ln16) * 72 + g * 8;
        hfv8 kh0 = *(const hfv8*)&sKh[ro], kh1 = *(const hfv8*)&sKh[ro + 32];
        fv4 sv = {};
        __builtin_amdgcn_s_setprio(1);
        sv = __builtin_amdgcn_mfma_f32_16x16x32_f16(kh0, qh[s][0], sv, 0, 0, 0);
        sv = __builtin_amdgcn_mfma_f32_16x16x32_f16(kh1, qh[s][1], sv, 0, 0, 0);
        __builtin_amdgcn_s_setprio(0);
        sc[kt] = sv;
      }
      float pmax = -3.0e38f;
#pragma unroll
      for (int kt = 0; kt < 4; ++kt)
#pragma unroll
        for (int r = 0; r < 4; ++r) {
          const float v = __builtin_fmaf(sc[kt][r], 0.125f, madd[kt][r]);
          sc[kt][r] = v;
          pmax = fmaxf(pmax, v);
        }
      pmax = fmaxf(pmax, __shfl_xor(pmax, 16));
      pmax = fmaxf(pmax, __shfl_xor(pmax, 32));
      if (pmax > m_run[s] + 8.f) {
        const float resc = __expf(m_run[s] - pmax);
        l_run[s] *= resc;
#pragma unroll
        for (int et = 0; et < 4; ++et)
#pragma unroll
          for (int r = 0; r < 4; ++r) O[s][et][r] *= resc;
        m_run[s] = pmax;
      }
      float psum = 0.f;
#pragma unroll
      for (int kt = 0; kt < 4; ++kt) {
        u16v4 pv;
#pragma unroll
        for (int r = 0; r < 4; ++r) {
          const unsigned short hb = f2h(__expf(sc[kt][r] - m_run[s]));
          pv[r] = hb;
          psum += h2f(hb);
        }
        *(u16v4*)&sP[w][ln16 * 72 + kt * 16 + g * 4] = pv;
      }
      psum += __shfl_xor(psum, 16);
      psum += __shfl_xor(psum, 32);
      l_run[s] += psum;

      hfv8 pf0 = *(const hfv8*)&sP[w][ln16 * 72 + g * 8];
      hfv8 pf1 = *(const hfv8*)&sP[w][ln16 * 72 + 32 + g * 8];
      __builtin_amdgcn_s_setprio(1);
#pragma unroll
      for (int et = 0; et < 4; ++et) {
        const int rb = (et * 16 + ln16) * 64;
        hfv8 vh0 = *(const hfv8*)&sVTh[rb + ((g * 8) ^ rsw)];
        hfv8 vh1 = *(const hfv8*)&sVTh[rb + ((g * 8 + 32) ^ rsw)];
        fv4 o = O[s][et];
        o = __builtin_amdgcn_mfma_f32_16x16x32_f16(vh0, pf0, o, 0, 0, 0);
        o = __builtin_amdgcn_mfma_f32_16x16x32_f16(vh1, pf1, o, 0, 0, 0);
        O[s][et] = o;
      }
      __builtin_amdgcn_s_setprio(0);
    }
  }

  __syncthreads();
  {
    const int e2 = (tid & 31) * 2, d4 = (tid >> 5) * 4;
    const float* Memp = Mem + (long)shb * 4096;
    fv2 ld[4];
#pragma unroll
    for (int i = 0; i < 4; ++i) ld[i] = *(const fv2*)&Memp[(d4 + i) * 64 + e2];
#pragma unroll
    for (int je = 0; je < 2; ++je) {
      u16v4 hv;
#pragma unroll
      for (int i = 0; i < 4; ++i) hv[i] = f2h(ld[i][je]);
      *(u16v4*)&sKh[(e2 + je) * 72 + d4] = hv;
    }
  }
  if (tid < 64) {
    sZ[tid] = Zp[(long)shb * 64 + tid];
    sGate[tid] = 1.f / (1.f + __expf(-betas[h * 64 + tid]));
  }
  __syncthreads();

#pragma unroll
  for (int s = 0; s < 2; ++s) {
    float dpart = 0.f;
#pragma unroll
    for (int dt = 0; dt < 2; ++dt) {
      u16v8 ah;
#pragma unroll
      for (int j = 0; j < 8; ++j) {
        const float xv = (float)qh[s][dt][j];
        const float a = xv > 0.f ? xv + 1.f : __expf(xv);
        dpart += a * sZ[dt * 32 + g * 8 + j];
        ah[j] = f2h(a);
      }
      qh[s][dt] = __builtin_bit_cast(hfv8, ah);
    }
    dpart += __shfl_xor(dpart, 16);
    dpart += __shfl_xor(dpart, 32);
    const float invden = 1.f / (dpart + 1e-9f);
    const float invl = 1.f / l_run[s];

    const long obase = (long)qglob[s] * D_DIM + h * 64;
#pragma unroll
    for (int et = 0; et < 4; ++et) {
      const int ro = (et * 16 + ln16) * 72 + g * 8;
      hfv8 mh0 = *(const hfv8*)&sKh[ro], mh1 = *(const hfv8*)&sKh[ro + 32];
      fv4 o = {};
      o = __builtin_amdgcn_mfma_f32_16x16x32_f16(mh0, qh[s][0], o, 0, 0, 0);
      o = __builtin_amdgcn_mfma_f32_16x16x32_f16(mh1, qh[s][1], o, 0, 0, 0);
      const fv4 gt = *(const fv4*)&sGate[et * 16 + g * 4];
      u16v4 st;
#pragma unroll
      for (int r = 0; r < 4; ++r) {
        const float att = gt[r] * o[r] * invden + (1.f - gt[r]) * O[s][et][r] * invl;
        st[r] = f2h(att);
      }
      *(u16v4*)&Op16[obase + et * 16 + g * 4] = st;
    }
  }
}

// ---------------- host launch ----------------
extern "C" void kernel_launch(void* const* d_in, const int* in_sizes, int n_in,
                              void* d_out, int out_size, void* d_ws, size_t ws_size,
                              hipStream_t stream) {
  (void)in_sizes; (void)n_in; (void)out_size;
  const float* x     = (const float*)d_in[0];
  const int*   mask  = (const int*)d_in[1];
  const float* wq    = (const float*)d_in[2];
  const float* wk    = (const float*)d_in[3];
  const float* wv    = (const float*)d_in[4];
  const float* wo    = (const float*)d_in[5];
  const float* wob   = (const float*)d_in[6];
  const float* betas = (const float*)d_in[7];
  float* out = (float*)d_out;

  const size_t TOK = (size_t)M_TOK * D_DIM;  // 33.5M elements
  char* ws = (char*)d_ws;
  size_t off = 0;
  auto alloc = [&](size_t bytes) {
    char* p = ws + off;
    off += (bytes + 255) & ~(size_t)255;
    return p;
  };
  unsigned short* wqkv16 = (unsigned short*)alloc((size_t)3 * D_DIM * D_DIM * 2);
  unsigned short* wo16   = (unsigned short*)alloc((size_t)D_DIM * D_DIM * 2);
  unsigned short* x16 = (unsigned short*)alloc(TOK * 2);  // 64 MiB
  unsigned short* q16 = (unsigned short*)alloc(TOK * 2);
  unsigned short* k16 = (unsigned short*)alloc(TOK * 2);
  unsigned short* v16 = (unsigned short*)alloc(TOK * 2);
  float* U   = (float*)alloc((size_t)B_DIM * NSEG * H_NUM * 4096 * 4);
  float* Mem = (float*)alloc((size_t)B_DIM * NSEG * H_NUM * 4096 * 4);
  float* Zs  = (float*)alloc((size_t)B_DIM * NSEG * H_NUM * 64 * 4);
  float* Zp  = (float*)alloc((size_t)B_DIM * NSEG * H_NUM * 64 * 4);
  unsigned short* att16 = x16;  // x16 dead after QKV GEMM — reuse

  if (off > ws_size) return;

  conv_all<<<2304, 256, 0, stream>>>(wq, wk, wv, wo, x, wqkv16, wo16, x16);

  const int qkvGrid = 24 * (M_TOK / 256);  // 3072 blocks
  gemm_bt<1><<<qkvGrid, 256, 0, stream>>>(
      (const _Float16*)x16, (const _Float16*)wqkv16, nullptr, nullptr,
      q16, k16, v16, M_TOK, 24, D_DIM);

  seg_outer_mfma<<<B_DIM * NSEG * H_NUM, 256, 0, stream>>>(k16, v16, U, Zs);
  seg_prefix<<<dim3(B_DIM * H_NUM, 8), 256, 0, stream>>>(U, Zs, Mem, Zp);

  attn_seg_mfma<<<B_DIM * NSEG * H_NUM * 2, 512, 0, stream>>>(
      q16, k16, v16, mask, Mem, Zp, betas, att16);

  const int oGrid = 8 * (M_TOK / 256);  // 1024 blocks
  gemm_bt<0><<<oGrid, 256, 0, stream>>>(
      (const _Float16*)att16, (const _Float16*)wo16, out, wob,
      nullptr, nullptr, nullptr, M_TOK, 8, D_DIM);
}

// Round 22
// 574.013 us; speedup vs baseline: 1.0473x; 1.0473x over previous
//
#include <hip/hip_runtime.h>

typedef float fv2 __attribute__((ext_vector_type(2)));
typedef float fv4 __attribute__((ext_vector_type(4)));
typedef _Float16 hfv8 __attribute__((ext_vector_type(8)));
typedef unsigned short u16v4 __attribute__((ext_vector_type(4)));
typedef unsigned short u16v8 __attribute__((ext_vector_type(8)));

#define B_DIM 4
#define L_DIM 8192
#define D_DIM 1024
#define H_NUM 16
#define NSEG 16
#define SEG_S 512
#define M_TOK (B_DIM * L_DIM)  // 32768

__device__ __forceinline__ unsigned short f2h(float f) {
  return __builtin_bit_cast(unsigned short, (_Float16)f);  // v_cvt_f16_f32 RNE
}
__device__ __forceinline__ float h2f(unsigned short u) {
  return (float)__builtin_bit_cast(_Float16, u);
}

// ---------------- fused fp32 -> fp16 conversions (weights + x, ONE launch) ----------------
__global__ __launch_bounds__(256) void conv_all(
    const float* __restrict__ wq, const float* __restrict__ wk,
    const float* __restrict__ wv, const float* __restrict__ wo,
    const float* __restrict__ x,
    unsigned short* __restrict__ wqkv16, unsigned short* __restrict__ wo16,
    unsigned short* __restrict__ x16) {
  const int W4 = D_DIM * D_DIM / 4;
  const int X4 = (M_TOK * D_DIM) / 4;
  const int blk = blockIdx.x;
  const float* src;
  unsigned short* dst;
  int n4, bid0, nblk;
  if (blk < 64)        { src = wq; dst = wqkv16;                              n4 = W4; bid0 = 0;   nblk = 64; }
  else if (blk < 128)  { src = wk; dst = wqkv16 + (size_t)D_DIM * D_DIM;      n4 = W4; bid0 = 64;  nblk = 64; }
  else if (blk < 192)  { src = wv; dst = wqkv16 + (size_t)2 * D_DIM * D_DIM;  n4 = W4; bid0 = 128; nblk = 64; }
  else if (blk < 256)  { src = wo; dst = wo16;                                n4 = W4; bid0 = 192; nblk = 64; }
  else                 { src = x;  dst = x16;                                 n4 = X4; bid0 = 256; nblk = 2048; }
  const int stride = nblk * 256;
  for (int i = (blk - bid0) * 256 + threadIdx.x; i < n4; i += stride) {
    fv4 v = reinterpret_cast<const fv4*>(src)[i];
    u16v4 p;
#pragma unroll
    for (int j = 0; j < 4; ++j) p[j] = f2h(v[j]);
    reinterpret_cast<u16v4*>(dst)[i] = p;
  }
}

// ---------------- C = A @ B^T, fp16 MFMA, gload_lds, wide wave tile ----------------
// VERIFIED r16/r18/r20 config: block 256x128, 4 waves, wave tile 128x64; 3 LDS
// buffers, depth-2 prefetch, counted vmcnt(6) (T4), ONE barrier per phase.
template <int QKV>
__global__ __launch_bounds__(256, 2) void gemm_bt(
    const _Float16* __restrict__ A16, const _Float16* __restrict__ B16,
    float* __restrict__ C, const float* __restrict__ bias,
    unsigned short* __restrict__ Oq, unsigned short* __restrict__ Ok,
    unsigned short* __restrict__ Ov, int M, int NTILES, int K) {
  __shared__ _Float16 sA[3][8192];  // 256 rows x 32 k
  __shared__ _Float16 sB[3][4096];  // 128 rows x 32 k
  const int tid = threadIdx.x;
  const int lane = tid & 63;
  const int wv = tid >> 6;
  const int wr = wv >> 1, wc = wv & 1;
  const int g = lane >> 4, ln16 = lane & 15;

  const int hw = blockIdx.x;
  const int xcd = hw & 7;
  const int rem = hw >> 3;
  const int ntile = rem % NTILES;
  const int yhi = rem / NTILES;
  const int mtile = yhi * 8 + xcd;
  const int mBase = mtile * 256;
  const int nBase = ntile * 128;

  fv4 acc[8][4] = {};

  const int srow = lane >> 2;
  const int cgx = ((lane & 3) ^ ((lane >> 3) & 3)) * 8;
  const long aStageBase = (long)(mBase + wv * 64 + srow) * K + cgx;
  const long bStageBase = (long)(nBase + wv * 32 + srow) * K + cgx;
  const int rgx = (g ^ ((ln16 >> 1) & 3)) * 8;
  const int arow0 = wr * 128 + ln16;
  const int brow0 = wc * 64 + ln16;

  auto STAGE = [&](int t, int bi) {
#pragma unroll
    for (int i = 0; i < 4; ++i)
      __builtin_amdgcn_global_load_lds(
          (const __attribute__((address_space(1))) void*)(A16 + aStageBase + (long)i * 16 * K + t * 32),
          (__attribute__((address_space(3))) void*)&sA[bi][wv * 2048 + i * 512], 16, 0, 0);
#pragma unroll
    for (int i = 0; i < 2; ++i)
      __builtin_amdgcn_global_load_lds(
          (const __attribute__((address_space(1))) void*)(B16 + bStageBase + (long)i * 16 * K + t * 32),
          (__attribute__((address_space(3))) void*)&sB[bi][wv * 1024 + i * 512], 16, 0, 0);
  };
  auto COMPUTE = [&](int bi) {
    hfv8 fa[8], fb[4];
#pragma unroll
    for (int i = 0; i < 4; ++i)
      fa[i] = *(const hfv8*)&sA[bi][(arow0 + i * 16) * 32 + rgx];
    fb[0] = *(const hfv8*)&sB[bi][(brow0) * 32 + rgx];
    fb[1] = *(const hfv8*)&sB[bi][(brow0 + 16) * 32 + rgx];
    __builtin_amdgcn_s_setprio(1);
#pragma unroll
    for (int i = 0; i < 4; ++i)
#pragma unroll
      for (int j = 0; j < 2; ++j)
        acc[i][j] = __builtin_amdgcn_mfma_f32_16x16x32_f16(fa[i], fb[j], acc[i][j], 0, 0, 0);
    __builtin_amdgcn_s_setprio(0);
    fb[2] = *(const hfv8*)&sB[bi][(brow0 + 32) * 32 + rgx];
    fb[3] = *(const hfv8*)&sB[bi][(brow0 + 48) * 32 + rgx];
    __builtin_amdgcn_s_setprio(1);
#pragma unroll
    for (int i = 0; i < 4; ++i)
#pragma unroll
      for (int j = 2; j < 4; ++j)
        acc[i][j] = __builtin_amdgcn_mfma_f32_16x16x32_f16(fa[i], fb[j], acc[i][j], 0, 0, 0);
    __builtin_amdgcn_s_setprio(0);
#pragma unroll
    for (int i = 4; i < 8; ++i)
      fa[i] = *(const hfv8*)&sA[bi][(arow0 + i * 16) * 32 + rgx];
    __builtin_amdgcn_s_setprio(1);
#pragma unroll
    for (int i = 4; i < 8; ++i)
#pragma unroll
      for (int j = 0; j < 4; ++j)
        acc[i][j] = __builtin_amdgcn_mfma_f32_16x16x32_f16(fa[i], fb[j], acc[i][j], 0, 0, 0);
    __builtin_amdgcn_s_setprio(0);
  };

  const int NT = K / 32;  // 32
  STAGE(0, 0);
  STAGE(1, 1);
  for (int t = 0; t < NT; ++t) {
    if (t < NT - 1)
      asm volatile("s_waitcnt vmcnt(6)" ::: "memory");
    else
      asm volatile("s_waitcnt vmcnt(0)" ::: "memory");
    __builtin_amdgcn_s_barrier();
    if (t + 2 < NT) STAGE(t + 2, (t + 2) % 3);
    COMPUTE(t % 3);
    asm volatile("s_waitcnt lgkmcnt(0)" ::: "memory");
  }

  const int crow0 = mBase + wr * 128 + ((lane >> 4) << 2);
  const int ccol0 = nBase + wc * 64 + (lane & 15);
  if (QKV) {
    const int which = nBase >> 10;
    unsigned short* outs = (which == 0) ? Oq : (which == 1) ? Ok : Ov;
    const int colb = ccol0 & 1023;
#pragma unroll
    for (int j = 0; j < 4; ++j) {
      const int col = colb + j * 16;
#pragma unroll
      for (int i = 0; i < 8; ++i) {
        const long rb = (long)(crow0 + i * 16) * 1024 + col;
#pragma unroll
        for (int r = 0; r < 4; ++r)
          outs[rb + (long)r * 1024] = f2h(acc[i][j][r]);
      }
    }
  } else {
    float bv[4];
#pragma unroll
    for (int j = 0; j < 4; ++j) bv[j] = bias ? bias[ccol0 + j * 16] : 0.f;
#pragma unroll
    for (int j = 0; j < 4; ++j) {
      const int col = ccol0 + j * 16;
#pragma unroll
      for (int i = 0; i < 8; ++i) {
        const long rb = (long)(crow0 + i * 16) * 1024 + col;
#pragma unroll
        for (int r = 0; r < 4; ++r)
          C[rb + (long)r * 1024] = acc[i][j][r] + bv[j];
      }
    }
  }
}

// ---------------- per-(b,seg,h) outer products: U = akT.v, ak split fp16 ----------------
__global__ __launch_bounds__(256) void seg_outer_mfma(
    const unsigned short* __restrict__ K16, const unsigned short* __restrict__ V16,
    float* __restrict__ U, float* __restrict__ Zs) {
  __shared__ _Float16 sAh[64 * 64], sAl[64 * 64];
  __shared__ _Float16 sVh[64 * 64];
  __shared__ float sZf[64];
  const int bid = blockIdx.x;
  const int b = bid >> 8, seg = (bid >> 4) & 15, h = bid & 15;
  const int tid = threadIdx.x;
  const int lane = tid & 63, w = tid >> 6;
  const int g = lane >> 4, ln16 = lane & 15;
  const long base = ((long)b * L_DIM + (long)seg * SEG_S) * D_DIM + h * 64;

  if (tid < 64) sZf[tid] = 0.f;
  fv4 acc[4] = {};
  float zacc = 0.f;
  const int strow = tid & 63;
  const int sg0 = (tid >> 6) * 16;
  const int wsw = (strow & 7) << 3;
  const int rsw = (ln16 & 7) << 3;

  for (int c = 0; c < 8; ++c) {
    __syncthreads();
#pragma unroll
    for (int jj = 0; jj < 2; ++jj) {
      u16v8 ah, al, vh;
#pragma unroll
      for (int i = 0; i < 8; ++i) {
        const long gidx = base + (long)(c * 64 + sg0 + jj * 8 + i) * D_DIM + strow;
        const float kv = h2f(K16[gidx]);
        const float a = kv > 0.f ? kv + 1.f : __expf(kv);
        zacc += a;
        const unsigned short hb = f2h(a);
        ah[i] = hb;
        al[i] = f2h(a - h2f(hb));
        vh[i] = V16[gidx];
      }
      const int col = (sg0 + jj * 8) ^ wsw;
      *(u16v8*)&sAh[strow * 64 + col] = ah;
      *(u16v8*)&sAl[strow * 64 + col] = al;
      *(u16v8*)&sVh[strow * 64 + col] = vh;
    }
    __syncthreads();
#pragma unroll
    for (int kf = 0; kf < 2; ++kf) {
      const int so = (kf * 32 + g * 8) ^ rsw;
      hfv8 aH = *(const hfv8*)&sAh[(w * 16 + ln16) * 64 + so];
      hfv8 aL = *(const hfv8*)&sAl[(w * 16 + ln16) * 64 + so];
      __builtin_amdgcn_s_setprio(1);
#pragma unroll
      for (int et = 0; et < 4; ++et) {
        hfv8 bH = *(const hfv8*)&sVh[(et * 16 + ln16) * 64 + so];
        acc[et] = __builtin_amdgcn_mfma_f32_16x16x32_f16(aH, bH, acc[et], 0, 0, 0);
        acc[et] = __builtin_amdgcn_mfma_f32_16x16x32_f16(aL, bH, acc[et], 0, 0, 0);
      }
      __builtin_amdgcn_s_setprio(0);
    }
  }
  atomicAdd(&sZf[strow], zacc);
  __syncthreads();

  const long ub = (long)bid * 4096;
#pragma unroll
  for (int et = 0; et < 4; ++et)
#pragma unroll
    for (int r = 0; r < 4; ++r)
      U[ub + (long)(w * 16 + g * 4 + r) * 64 + et * 16 + ln16] = acc[et][r];
  if (tid < 64) Zs[(long)bid * 64 + tid] = sZf[tid];
}

// ---------------- exclusive prefix over segments (per b,h) ----------------
__global__ __launch_bounds__(256) void seg_prefix(
    const float* __restrict__ U, const float* __restrict__ Zs,
    float* __restrict__ Mem, float* __restrict__ Zp) {
  const int bh = blockIdx.x;
  const int b = bh >> 4, h = bh & 15;
  const int jc = blockIdx.y;
  const int tid = threadIdx.x;
  for (int j = jc * 512 + tid; j < jc * 512 + 512; j += 256) {
    float run = 0.f;
#pragma unroll
    for (int t = 0; t < NSEG; ++t) {
      const long idx = ((long)(b * 256 + t * 16 + h)) * 4096 + j;
      Mem[idx] = run;
      run += U[idx];
    }
  }
  if (jc == 0 && tid < 64) {
    float run = 0.f;
#pragma unroll
    for (int t = 0; t < NSEG; ++t) {
      const long idx = ((long)(b * 256 + t * 16 + h)) * 64 + tid;
      Zp[idx] = run;
      run += Zs[idx];
    }
  }
}

// ---------------- MFMA segment attention: 2 query-sets per block (r18/r20 verbatim) ----------------
__global__ __launch_bounds__(512, 4) void attn_seg_mfma(
    const unsigned short* __restrict__ Q16, const unsigned short* __restrict__ K16,
    const unsigned short* __restrict__ V16, const int* __restrict__ mask,
    const float* __restrict__ Mem, const float* __restrict__ Zp,
    const float* __restrict__ betas, unsigned short* __restrict__ Op16) {
  __shared__ _Float16 sKh[64 * 72];   // K chunk [key][d]; later Mem^T [e][d]
  __shared__ _Float16 sVTh[64 * 64];  // V^T [e][key], swizzled
  __shared__ _Float16 sP[8][16 * 72]; // per-wave P fp16 [q][key] (reused per set)
  __shared__ float sMadd[64], sZ[64], sGate[64];

  const int bx = (blockIdx.x & 7) * 256 + (blockIdx.x >> 3);  // T1 bijective
  const int qpair = bx & 1, h = (bx >> 1) & 15, seg = (bx >> 5) & 15, b = bx >> 9;
  const int shb = b * 256 + seg * 16 + h;
  const int tid = threadIdx.x;
  const int lane = tid & 63, w = tid >> 6;
  const int g = lane >> 4, ln16 = lane & 15;
  const int rsw = (ln16 & 7) << 3;

  int qglob[2];
  hfv8 qh[2][2];
#pragma unroll
  for (int s = 0; s < 2; ++s) {
    qglob[s] = b * L_DIM + seg * SEG_S + qpair * 256 + s * 128 + w * 16 + ln16;
    const long qb = (long)qglob[s] * D_DIM + h * 64;
#pragma unroll
    for (int dt = 0; dt < 2; ++dt)
      qh[s][dt] = *(const hfv8*)&Q16[qb + dt * 32 + g * 8];
  }

  fv4 O[2][4] = {};
  float m_run[2] = {-1e30f, -1e30f}, l_run[2] = {0.f, 0.f};
  const long kvbase0 = ((long)b * L_DIM + (long)seg * SEG_S) * D_DIM + h * 64;

  for (int c = 0; c < 8; ++c) {
    __syncthreads();
    {  // stage K [64 key][64 d]
      const int row = tid >> 3, d0 = (tid & 7) * 8;
      const long ga = kvbase0 + (long)(c * 64 + row) * D_DIM + d0;
      *(u16v8*)&sKh[row * 72 + d0] = *(const u16v8*)&K16[ga];
    }
    {  // stage V^T [64 e][64 key], XOR-swizzled
      const int e = tid & 63, kg = (tid >> 6) * 8;
      u16v8 hv;
#pragma unroll
      for (int j = 0; j < 8; ++j)
        hv[j] = V16[kvbase0 + (long)(c * 64 + kg + j) * D_DIM + e];
      *(u16v8*)&sVTh[e * 64 + (kg ^ ((e & 7) << 3))] = hv;
    }
    if (tid < 64)
      sMadd[tid] = (mask[b * L_DIM + seg * SEG_S + c * 64 + tid] == 0) ? -1e9f : 0.f;
    __syncthreads();

    fv4 madd[4];
#pragma unroll
    for (int kt = 0; kt < 4; ++kt) madd[kt] = *(const fv4*)&sMadd[kt * 16 + g * 4];

#pragma unroll
    for (int s = 0; s < 2; ++s) {
      fv4 sc[4];
#pragma unroll
      for (int kt = 0; kt < 4; ++kt) {
        const int ro = (kt * 16 + ln16) * 72 + g * 8;
        hfv8 kh0 = *(const hfv8*)&sKh[ro], kh1 = *(const hfv8*)&sKh[ro + 32];
        fv4 sv = {};
        __builtin_amdgcn_s_setprio(1);
        sv = __builtin_amdgcn_mfma_f32_16x16x32_f16(kh0, qh[s][0], sv, 0, 0, 0);
        sv = __builtin_amdgcn_mfma_f32_16x16x32_f16(kh1, qh[s][1], sv, 0, 0, 0);
        __builtin_amdgcn_s_setprio(0);
        sc[kt] = sv;
      }
      float pmax = -3.0e38f;
#pragma unroll
      for (int kt = 0; kt < 4; ++kt)
#pragma unroll
        for (int r = 0; r < 4; ++r) {
          const float v = __builtin_fmaf(sc[kt][r], 0.125f, madd[kt][r]);
          sc[kt][r] = v;
          pmax = fmaxf(pmax, v);
        }
      pmax = fmaxf(pmax, __shfl_xor(pmax, 16));
      pmax = fmaxf(pmax, __shfl_xor(pmax, 32));
      if (pmax > m_run[s] + 8.f) {
        const float resc = __expf(m_run[s] - pmax);
        l_run[s] *= resc;
#pragma unroll
        for (int et = 0; et < 4; ++et)
#pragma unroll
          for (int r = 0; r < 4; ++r) O[s][et][r] *= resc;
        m_run[s] = pmax;
      }
      float psum = 0.f;
#pragma unroll
      for (int kt = 0; kt < 4; ++kt) {
        u16v4 pv;
#pragma unroll
        for (int r = 0; r < 4; ++r) {
          const unsigned short hb = f2h(__expf(sc[kt][r] - m_run[s]));
          pv[r] = hb;
          psum += h2f(hb);
        }
        *(u16v4*)&sP[w][ln16 * 72 + kt * 16 + g * 4] = pv;
      }
      psum += __shfl_xor(psum, 16);
      psum += __shfl_xor(psum, 32);
      l_run[s] += psum;

      hfv8 pf0 = *(const hfv8*)&sP[w][ln16 * 72 + g * 8];
      hfv8 pf1 = *(const hfv8*)&sP[w][ln16 * 72 + 32 + g * 8];
      __builtin_amdgcn_s_setprio(1);
#pragma unroll
      for (int et = 0; et < 4; ++et) {
        const int rb = (et * 16 + ln16) * 64;
        hfv8 vh0 = *(const hfv8*)&sVTh[rb + ((g * 8) ^ rsw)];
        hfv8 vh1 = *(const hfv8*)&sVTh[rb + ((g * 8 + 32) ^ rsw)];
        fv4 o = O[s][et];
        o = __builtin_amdgcn_mfma_f32_16x16x32_f16(vh0, pf0, o, 0, 0, 0);
        o = __builtin_amdgcn_mfma_f32_16x16x32_f16(vh1, pf1, o, 0, 0, 0);
        O[s][et] = o;
      }
      __builtin_amdgcn_s_setprio(0);
    }
  }

  // ---- memory-read term (staged once, used by both sets) ----
  __syncthreads();
  {
    const int e2 = (tid & 31) * 2, d4 = (tid >> 5) * 4;
    const float* Memp = Mem + (long)shb * 4096;
    fv2 ld[4];
#pragma unroll
    for (int i = 0; i < 4; ++i) ld[i] = *(const fv2*)&Memp[(d4 + i) * 64 + e2];
#pragma unroll
    for (int je = 0; je < 2; ++je) {
      u16v4 hv;
#pragma unroll
      for (int i = 0; i < 4; ++i) hv[i] = f2h(ld[i][je]);
      *(u16v4*)&sKh[(e2 + je) * 72 + d4] = hv;
    }
  }
  if (tid < 64) {
    sZ[tid] = Zp[(long)shb * 64 + tid];
    sGate[tid] = 1.f / (1.f + __expf(-betas[h * 64 + tid]));
  }
  __syncthreads();

#pragma unroll
  for (int s = 0; s < 2; ++s) {
    float dpart = 0.f;
#pragma unroll
    for (int dt = 0; dt < 2; ++dt) {
      u16v8 ah;
#pragma unroll
      for (int j = 0; j < 8; ++j) {
        const float xv = (float)qh[s][dt][j];
        const float a = xv > 0.f ? xv + 1.f : __expf(xv);
        dpart += a * sZ[dt * 32 + g * 8 + j];
        ah[j] = f2h(a);
      }
      qh[s][dt] = __builtin_bit_cast(hfv8, ah);
    }
    dpart += __shfl_xor(dpart, 16);
    dpart += __shfl_xor(dpart, 32);
    const float invden = 1.f / (dpart + 1e-9f);
    const float invl = 1.f / l_run[s];

    const long obase = (long)qglob[s] * D_DIM + h * 64;
#pragma unroll
    for (int et = 0; et < 4; ++et) {
      const int ro = (et * 16 + ln16) * 72 + g * 8;
      hfv8 mh0 = *(const hfv8*)&sKh[ro], mh1 = *(const hfv8*)&sKh[ro + 32];
      fv4 o = {};
      o = __builtin_amdgcn_mfma_f32_16x16x32_f16(mh0, qh[s][0], o, 0, 0, 0);
      o = __builtin_amdgcn_mfma_f32_16x16x32_f16(mh1, qh[s][1], o, 0, 0, 0);
      const fv4 gt = *(const fv4*)&sGate[et * 16 + g * 4];
      u16v4 st;
#pragma unroll
      for (int r = 0; r < 4; ++r) {
        const float att = gt[r] * o[r] * invden + (1.f - gt[r]) * O[s][et][r] * invl;
        st[r] = f2h(att);
      }
      *(u16v4*)&Op16[obase + et * 16 + g * 4] = st;
    }
  }
}

// ---------------- host launch ----------------
extern "C" void kernel_launch(void* const* d_in, const int* in_sizes, int n_in,
                              void* d_out, int out_size, void* d_ws, size_t ws_size,
                              hipStream_t stream) {
  (void)in_sizes; (void)n_in; (void)out_size;
  const float* x     = (const float*)d_in[0];
  const int*   mask  = (const int*)d_in[1];
  const float* wq    = (const float*)d_in[2];
  const float* wk    = (const float*)d_in[3];
  const float* wv    = (const float*)d_in[4];
  const float* wo    = (const float*)d_in[5];
  const float* wob   = (const float*)d_in[6];
  const float* betas = (const float*)d_in[7];
  float* out = (float*)d_out;

  const size_t TOK = (size_t)M_TOK * D_DIM;  // 33.5M elements
  char* ws = (char*)d_ws;
  size_t off = 0;
  auto alloc = [&](size_t bytes) {
    char* p = ws + off;
    off += (bytes + 255) & ~(size_t)255;
    return p;
  };
  unsigned short* wqkv16 = (unsigned short*)alloc((size_t)3 * D_DIM * D_DIM * 2);
  unsigned short* wo16   = (unsigned short*)alloc((size_t)D_DIM * D_DIM * 2);
  unsigned short* x16 = (unsigned short*)alloc(TOK * 2);  // 64 MiB
  unsigned short* q16 = (unsigned short*)alloc(TOK * 2);
  unsigned short* k16 = (unsigned short*)alloc(TOK * 2);
  unsigned short* v16 = (unsigned short*)alloc(TOK * 2);
  float* U   = (float*)alloc((size_t)B_DIM * NSEG * H_NUM * 4096 * 4);
  float* Mem = (float*)alloc((size_t)B_DIM * NSEG * H_NUM * 4096 * 4);
  float* Zs  = (float*)alloc((size_t)B_DIM * NSEG * H_NUM * 64 * 4);
  float* Zp  = (float*)alloc((size_t)B_DIM * NSEG * H_NUM * 64 * 4);
  unsigned short* att16 = x16;  // x16 dead after QKV GEMM — reuse

  if (off > ws_size) return;

  conv_all<<<2304, 256, 0, stream>>>(wq, wk, wv, wo, x, wqkv16, wo16, x16);

  // merged QKV: block tile 256x128, N = 3072 -> 24 N-tiles, 128 M-tiles
  const int qkvGrid = 24 * (M_TOK / 256);  // 3072 blocks
  gemm_bt<1><<<qkvGrid, 256, 0, stream>>>(
      (const _Float16*)x16, (const _Float16*)wqkv16, nullptr, nullptr,
      q16, k16, v16, M_TOK, 24, D_DIM);

  seg_outer_mfma<<<B_DIM * NSEG * H_NUM, 256, 0, stream>>>(k16, v16, U, Zs);
  seg_prefix<<<dim3(B_DIM * H_NUM, 8), 256, 0, stream>>>(U, Zs, Mem, Zp);

  attn_seg_mfma<<<B_DIM * NSEG * H_NUM * 2, 512, 0, stream>>>(
      q16, k16, v16, mask, Mem, Zp, betas, att16);

  const int oGrid = 8 * (M_TOK / 256);  // 1024 blocks
  gemm_bt<0><<<oGrid, 256, 0, stream>>>(
      (const _Float16*)att16, (const _Float16*)wo16, out, wob,
      nullptr, nullptr, nullptr, M_TOK, 8, D_DIM);
}